// Round 9
// baseline (173.602 us; speedup 1.0000x reference)
//
#include <hip/hip_runtime.h>
#include <cmath>

#define NPTS 8192
#define DIM 64
#define BT 128

// ws layout (float offsets) — unchanged
#define LEAF_F   0
#define LEAF_N   (3 * 8192 * 64)          // layout [z][cb][row]
#define ROWS_F   (LEAF_F + LEAF_N)
#define ROWS_N   (3 * 8192)
#define MEANS_F  (ROWS_F + ROWS_N)
#define NX_F     ((MEANS_F + 3 + 3) & ~3) // 16B-align
#define NY_F     (NX_F + 8192)
#define SPLIT_F  (NY_F + 8192)
#define SPLIT_ELEMS (NPTS * DIM)

// frag-major split layout: [rowtile t16][kc 0..1][quad 0..3][mrow 0..15][8]
// element (row = t16*16+mrow, k = q8*8+e) at t16*1024 + (q8>>2)*512 +
// (q8&3)*128 + mrow*8 + e  — serves BOTH 16x16x32 (q8 = kc*4 + (lane>>4))
// and 32x32x16 (q8 = c*2 + (lane>>5)) fragment reads.

typedef short bf16x8 __attribute__((ext_vector_type(8)));
typedef float f32x16 __attribute__((ext_vector_type(16)));
typedef unsigned short u16x8 __attribute__((ext_vector_type(8)));

__device__ __forceinline__ unsigned short f32_bf16_rne(float f) {
    unsigned u = __float_as_uint(f);
    return (unsigned short)((u + 0x7FFFu + ((u >> 16) & 1u)) >> 16);
}
__device__ __forceinline__ float bf16_f32(unsigned short h) {
    return __uint_as_float(((unsigned)h) << 16);
}

// raw v_exp_f32: bit-identical to exp2f for our argument range [-0.25, 0]
__device__ __forceinline__ float exp2_hw(float x) {
#if __has_builtin(__builtin_amdgcn_exp2f)
    return __builtin_amdgcn_exp2f(x);
#else
    float r;
    asm("v_exp_f32 %0, %1" : "=v"(r) : "v"(x));
    return r;
#endif
}

// single-instruction xor-lane shuffles (masks <= 16): ds_swizzle BitMode
#define SWZ_XOR1(x)  __int_as_float(__builtin_amdgcn_ds_swizzle(__float_as_int(x), 0x041F))
#define SWZ_XOR2(x)  __int_as_float(__builtin_amdgcn_ds_swizzle(__float_as_int(x), 0x081F))
#define SWZ_XOR4(x)  __int_as_float(__builtin_amdgcn_ds_swizzle(__float_as_int(x), 0x101F))
#define SWZ_XOR8(x)  __int_as_float(__builtin_amdgcn_ds_swizzle(__float_as_int(x), 0x201F))
#define SWZ_XOR16(x) __int_as_float(__builtin_amdgcn_ds_swizzle(__float_as_int(x), 0x401F))

// ---- prep v2: 8 threads/row, coalesced 32B loads, 16B ushort8 stores.
// Bit-identical split bytes + norms (R8, passed).
__global__ void prep_kernel(const float* __restrict__ x, const float* __restrict__ y,
                            unsigned short* __restrict__ Xh, unsigned short* __restrict__ Xl,
                            unsigned short* __restrict__ Yh, unsigned short* __restrict__ Yl,
                            float* __restrict__ nx, float* __restrict__ ny) {
    int gtid = blockIdx.x * 256 + threadIdx.x;   // 0..131071 = 16384 rows x 8
    int r = gtid >> 3;
    int m = gtid & 7;                            // handles k4 = {2m, 2m+1}
    int isY = r >= NPTS;
    int rr = isY ? r - NPTS : r;
    const float4* Rg = (const float4*)((isY ? y : x) + (size_t)rr * DIM);
    unsigned short* Hh = isY ? Yh : Xh;
    unsigned short* Hl = isY ? Yl : Xl;
    const int t16 = rr >> 4, mrow = rr & 15;
    float4 v0 = Rg[2 * m];
    float4 v1 = Rg[2 * m + 1];
    u16x8 h, l;
    h[0] = f32_bf16_rne(v0.x); l[0] = f32_bf16_rne(v0.x - bf16_f32(h[0]));
    h[1] = f32_bf16_rne(v0.y); l[1] = f32_bf16_rne(v0.y - bf16_f32(h[1]));
    h[2] = f32_bf16_rne(v0.z); l[2] = f32_bf16_rne(v0.z - bf16_f32(h[2]));
    h[3] = f32_bf16_rne(v0.w); l[3] = f32_bf16_rne(v0.w - bf16_f32(h[3]));
    h[4] = f32_bf16_rne(v1.x); l[4] = f32_bf16_rne(v1.x - bf16_f32(h[4]));
    h[5] = f32_bf16_rne(v1.y); l[5] = f32_bf16_rne(v1.y - bf16_f32(h[5]));
    h[6] = f32_bf16_rne(v1.z); l[6] = f32_bf16_rne(v1.z - bf16_f32(h[6]));
    h[7] = f32_bf16_rne(v1.w); l[7] = f32_bf16_rne(v1.w - bf16_f32(h[7]));
    int off = t16 * 1024 + (m >> 2) * 512 + (m & 3) * 128 + mrow * 8;
    *(u16x8*)(Hh + off) = h;
    *(u16x8*)(Hl + off) = l;
    float s0 = v0.x * v0.x;
    s0 = fmaf(v0.y, v0.y, s0); s0 = fmaf(v0.z, v0.z, s0); s0 = fmaf(v0.w, v0.w, s0);
    float s1 = v1.x * v1.x;
    s1 = fmaf(v1.y, v1.y, s1); s1 = fmaf(v1.z, v1.z, s1); s1 = fmaf(v1.w, v1.w, s1);
    float s = s0 + s1;
    s = s + SWZ_XOR1(s);
    s = s + SWZ_XOR2(s);
    s = s + SWZ_XOR4(s);
    if (m == 0) { if (isY) ny[rr] = s; else nx[rr] = s; }
}

// ---- main tile kernel, 32x32x16 MFMA version.
// Per wave: 32-row group (wr) x two 32x32 col tiles (wc half). 24 MFMA
// per wave (vs 48 with 16x16x32): same FLOPs, half the instructions,
// ~15% faster matrix rate. Same split bytes, same 3-product math,
// same rowsum/colsum trees; leaf-level summation order changes only.
// C/D layout (HW-verified): col=lane&31, row=(reg&3)+8*(reg>>2)+4*(lane>>5).
// A/B input: lane holds row/col = lane&31, k = (lane>>5)*8 + e.
__global__ __launch_bounds__(512, 3) void mmd_tile_kernel(
    const unsigned short* __restrict__ Xh, const unsigned short* __restrict__ Xl,
    const unsigned short* __restrict__ Yh, const unsigned short* __restrict__ Yl,
    const float* __restrict__ nx, const float* __restrict__ ny,
    float* __restrict__ leafs)
{
    // XCD-aware bijective swizzle: 8320 blocks = 8 XCDs x 1040 exactly.
    int id  = blockIdx.x + 65 * (blockIdx.y + 64 * blockIdx.z);  // 0..8319
    int nid = (id & 7) * 1040 + (id >> 3);
    int zb  = nid >= 4160;
    int rem = nid - zb * 4160;          // 0..4159
    int gj  = rem / 65;
    int gi  = rem - gj * 65;

    int zz, bx, by;
    if (zb == 1) {
        if (gi >= 64) return;
        zz = 2; bx = gi; by = gj;
    } else if (gi > gj) {
        zz = 0; by = gj; bx = gi - 1;
    } else {
        zz = 1; by = gi; bx = gj;
    }

    __shared__ float rowpart[2][BT];       // [cblk half][row]
    __shared__ float colpart[4][BT];       // [row group][col]

    const int t = threadIdx.x;
    const size_t arow = (size_t)by * BT;
    const size_t brow = (size_t)bx * BT;
    const int cb = bx;

    const unsigned short* pAh = (zz == 1) ? Yh : Xh;
    const unsigned short* pAl = (zz == 1) ? Yl : Xl;
    const unsigned short* pBh = (zz == 0) ? Xh : Yh;
    const unsigned short* pBl = (zz == 0) ? Xl : Yl;
    const float* nA = (zz == 1) ? ny : nx;
    const float* nB = (zz == 0) ? nx : ny;

    const int lane = t & 63;
    const int wv   = t >> 6;               // 0..7
    const int wr   = wv & 3;               // row group (32 rows)
    const int wc   = wv >> 2;              // col group (64 cols)
    const int c5   = lane & 31;
    const int hi   = lane >> 5;
    const int mrow = lane & 15;
    const int m16  = c5 >> 4;

    const bool domirror = (zz < 2) && (bx > by);

    // norms (L2-resident broadcast)
    float sa[16];
    #pragma unroll
    for (int j = 0; j < 16; ++j)
        sa[j] = nA[arow + wr * 32 + (j & 3) + 8 * (j >> 2) + 4 * hi];
    float sb0 = nB[brow + wc * 64 + c5];
    float sb1 = nB[brow + wc * 64 + 32 + c5];

    // A fragments: 4 k-chunks x h/l (32 VGPR)
    const int aT = by * 8 + wr * 2 + m16;
    bf16x8 Ahf[4], Alf[4];
    #pragma unroll
    for (int c = 0; c < 4; ++c) {
        int q8 = c * 2 + hi;
        int off = aT * 1024 + (q8 >> 2) * 512 + (q8 & 3) * 128 + mrow * 8;
        Ahf[c] = *(const bf16x8*)(pAh + off);
        Alf[c] = *(const bf16x8*)(pAl + off);
    }
    // B fragments: 2 tiles x 4 chunks x h/l (64 VGPR)
    bf16x8 Bhf[2][4], Blf[2][4];
    #pragma unroll
    for (int tt = 0; tt < 2; ++tt) {
        int bT = bx * 8 + wc * 4 + tt * 2 + m16;
        #pragma unroll
        for (int c = 0; c < 4; ++c) {
            int q8 = c * 2 + hi;
            int off = bT * 1024 + (q8 >> 2) * 512 + (q8 & 3) * 128 + mrow * 8;
            Bhf[tt][c] = *(const bf16x8*)(pBh + off);
            Blf[tt][c] = *(const bf16x8*)(pBl + off);
        }
    }

    f32x16 acc0 = {0.f,0.f,0.f,0.f,0.f,0.f,0.f,0.f,0.f,0.f,0.f,0.f,0.f,0.f,0.f,0.f};
    f32x16 acc1 = {0.f,0.f,0.f,0.f,0.f,0.f,0.f,0.f,0.f,0.f,0.f,0.f,0.f,0.f,0.f,0.f};

    __builtin_amdgcn_s_setprio(1);
    #pragma unroll
    for (int c = 0; c < 4; ++c) {
        acc0 = __builtin_amdgcn_mfma_f32_32x32x16_bf16(Ahf[c], Bhf[0][c], acc0, 0, 0, 0);
        acc1 = __builtin_amdgcn_mfma_f32_32x32x16_bf16(Ahf[c], Bhf[1][c], acc1, 0, 0, 0);
        acc0 = __builtin_amdgcn_mfma_f32_32x32x16_bf16(Ahf[c], Blf[0][c], acc0, 0, 0, 0);
        acc1 = __builtin_amdgcn_mfma_f32_32x32x16_bf16(Ahf[c], Blf[1][c], acc1, 0, 0, 0);
        acc0 = __builtin_amdgcn_mfma_f32_32x32x16_bf16(Alf[c], Bhf[0][c], acc0, 0, 0, 0);
        acc1 = __builtin_amdgcn_mfma_f32_32x32x16_bf16(Alf[c], Bhf[1][c], acc1, 0, 0, 0);
    }
    __builtin_amdgcn_s_setprio(0);

    // ---- epilogue: k = exp2(sqd * -log2e/4096), per-element math as before
    const float SCL = (float)(-1.4426950408889634 / 4096.0);
    float k0[16], k1[16];
    #pragma unroll
    for (int j = 0; j < 16; ++j) {
        k0[j] = exp2_hw((sa[j] + sb0 - 2.0f * acc0[j]) * SCL);
        k1[j] = exp2_hw((sa[j] + sb1 - 2.0f * acc1[j]) * SCL);
    }

    // ---- row reduce: 5-level split-butterfly over col bits b0..b4
    float rsv[16];
    #pragma unroll
    for (int j = 0; j < 16; ++j) rsv[j] = k0[j] + k1[j];

    const int b0 = lane & 1;
    const int b1 = (lane >> 1) & 1;
    const int b2 = (lane >> 2) & 1;
    const int b3 = (lane >> 3) & 1;
    const int b4 = (lane >> 4) & 1;

    float a8[8];
    #pragma unroll
    for (int i = 0; i < 8; ++i) {
        float snd = b0 ? rsv[i] : rsv[i + 8];
        float rcv = SWZ_XOR1(snd);
        a8[i] = (b0 ? rsv[i + 8] : rsv[i]) + rcv;      // keep j-bit3 = b0
    }
    float a4[4];
    #pragma unroll
    for (int i = 0; i < 4; ++i) {
        float snd = b1 ? a8[i] : a8[i + 4];
        float rcv = SWZ_XOR2(snd);
        a4[i] = (b1 ? a8[i + 4] : a8[i]) + rcv;        // keep j-bit2 = b1
    }
    float a2[2];
    #pragma unroll
    for (int i = 0; i < 2; ++i) {
        float snd = b2 ? a4[i] : a4[i + 2];
        float rcv = SWZ_XOR4(snd);
        a2[i] = (b2 ? a4[i + 2] : a4[i]) + rcv;        // keep j-bit1 = b2
    }
    {
        float snd = b3 ? a2[0] : a2[1];
        float rcv = SWZ_XOR8(snd);
        float a1  = (b3 ? a2[1] : a2[0]) + rcv;        // keep j-bit0 = b3
        float r64 = a1 + SWZ_XOR16(a1);                // full 64-col group sum
        // kept j = 8*b0+4*b1+2*b2+b3 -> row_off = 16*b0+8*b1+2*b2+b3+4*hi
        if (b4 == 0)
            rowpart[wc][wr * 32 + 16 * b0 + 8 * b1 + 2 * b2 + b3 + 4 * hi] = r64;
    }

    // ---- col reduce (mirror tiles): in-reg balanced 16-tree + xor32
    if (domirror) {
        float w0[16], w1[16];
        #pragma unroll
        for (int j = 0; j < 16; ++j) { w0[j] = k0[j]; w1[j] = k1[j]; }
        #pragma unroll
        for (int n = 8; n >= 1; n >>= 1)
            #pragma unroll
            for (int i = 0; i < 16; ++i)
                if (i < n) { w0[i] = w0[2*i] + w0[2*i+1]; w1[i] = w1[2*i] + w1[2*i+1]; }
        float f0 = w0[0] + __shfl_xor(w0[0], 32);      // sum over 32 rows
        float f1 = w1[0] + __shfl_xor(w1[0], 32);
        if (hi == 0) {
            colpart[wr][wc * 64 + c5]      = f0;
            colpart[wr][wc * 64 + 32 + c5] = f1;
        }
    }
    __syncthreads();

    // ---- combine halves/quarters, write leafs (unchanged)
    if (t < BT) {
        leafs[((size_t)zz * 64 + cb) * 8192 + arow + t] = rowpart[0][t] + rowpart[1][t];
        if (domirror) {
            leafs[((size_t)zz * 64 + by) * 8192 + brow + t] =
                (colpart[0][t] + colpart[1][t]) + (colpart[2][t] + colpart[3][t]);
        }
    }
}

// Phase B: rowsum, 4 threads/row, bit-exact split (R5/R7 verbatim)
__global__ void rowsum_kernel(const float* __restrict__ leafs, float* __restrict__ rowsums) {
    const int t = threadIdx.x;             // 0..255
    const int wv = t >> 6;                 // wave 0..3
    const int lane = t & 63;
    const int p = lane >> 4;               // leaf-quarter 0..3
    const int rlo = lane & 15;
    const int gr = blockIdx.x * 64 + wv * 16 + rlo;   // 0..24575
    const int z = gr >> 13;
    const int r = gr & 8191;
    const float* base = leafs + ((size_t)z * 64 + p * 16) * 8192 + r;
    float v[16];
    #pragma unroll
    for (int i = 0; i < 16; ++i) v[i] = base[(size_t)i * 8192];
    #pragma unroll
    for (int n = 8; n >= 1; n >>= 1)
        #pragma unroll
        for (int i = 0; i < 16; ++i)
            if (i < n) v[i] = v[2*i] + v[2*i+1];
    float s = v[0];
    float u = s + SWZ_XOR16(s);            // S0+S1 | S2+S3
    float w = u + __shfl_xor(u, 32);       // (S0+S1)+(S2+S3)
    if (p == 0) rowsums[gr] = w;
}

// Phase C+D fused, 3 parallel z-groups (R7 verbatim, known-good)
__global__ void colsum_kernel(const float* __restrict__ rowsums, float* __restrict__ out) {
    __shared__ float L[3][256];
    __shared__ float m[3];
    const int t  = threadIdx.x;            // 0..767
    const int z  = t >> 8;                 // 0..2
    const int tz = t & 255;
    {
        const float4* src = (const float4*)(rowsums + z * 8192);
        float w[32];
        #pragma unroll
        for (int i = 0; i < 8; ++i) {
            float4 q = src[tz * 8 + i];
            w[4*i+0] = q.x; w[4*i+1] = q.y; w[4*i+2] = q.z; w[4*i+3] = q.w;
        }
        #pragma unroll
        for (int n = 16; n >= 1; n >>= 1)
            #pragma unroll
            for (int i = 0; i < 32; ++i)
                if (i < n) w[i] = w[2*i] + w[2*i+1];
        L[z][tz] = w[0];
    }
    __syncthreads();
    for (int n = 128; n >= 1; n >>= 1) {
        float u = 0.f;
        if (tz < n) u = L[z][2*tz] + L[z][2*tz+1];
        __syncthreads();
        if (tz < n) L[z][tz] = u;
        __syncthreads();
    }
    if (tz == 0) m[z] = L[z][0] * (1.0f / 67108864.0f);
    __syncthreads();
    if (t == 0) {
        float t1 = m[0] + m[1];
        out[0] = t1 - 2.0f * m[2];
    }
}

extern "C" void kernel_launch(void* const* d_in, const int* in_sizes, int n_in,
                              void* d_out, int out_size, void* d_ws, size_t ws_size,
                              hipStream_t stream) {
    const float* x = (const float*)d_in[0];
    const float* y = (const float*)d_in[1];
    float* wsf     = (float*)d_ws;
    float* leafs   = wsf + LEAF_F;
    float* rowsums = wsf + ROWS_F;
    float* nx      = wsf + NX_F;
    float* ny      = wsf + NY_F;
    unsigned short* Xh = (unsigned short*)(wsf + SPLIT_F);
    unsigned short* Xl = Xh + SPLIT_ELEMS;
    unsigned short* Yh = Xl + SPLIT_ELEMS;
    unsigned short* Yl = Yh + SPLIT_ELEMS;

    prep_kernel<<<512, 256, 0, stream>>>(x, y, Xh, Xl, Yh, Yl, nx, ny);
    dim3 grid(65, 64, 2);
    mmd_tile_kernel<<<grid, 512, 0, stream>>>(Xh, Xl, Yh, Yl, nx, ny, leafs);
    rowsum_kernel<<<384, 256, 0, stream>>>(leafs, rowsums);
    colsum_kernel<<<1, 768, 0, stream>>>(rowsums, (float*)d_out);
}

// Round 10
// 129.464 us; speedup vs baseline: 1.3409x; 1.3409x over previous
//
#include <hip/hip_runtime.h>
#include <cmath>

#define NPTS 8192
#define DIM 64
#define BT 128

// ws layout (float offsets) — unchanged
#define LEAF_F   0
#define LEAF_N   (3 * 8192 * 64)          // layout [z][cb][row]
#define ROWS_F   (LEAF_F + LEAF_N)
#define ROWS_N   (3 * 8192)
#define MEANS_F  (ROWS_F + ROWS_N)
#define NX_F     ((MEANS_F + 3 + 3) & ~3) // 16B-align
#define NY_F     (NX_F + 8192)
#define SPLIT_F  (NY_F + 8192)
#define SPLIT_ELEMS (NPTS * DIM)

// frag-major split layout: [rowtile t16][kc 0..1][quad 0..3][mrow 0..15][8]

typedef short bf16x8 __attribute__((ext_vector_type(8)));
typedef float f32x4  __attribute__((ext_vector_type(4)));
typedef unsigned short u16x8 __attribute__((ext_vector_type(8)));

__device__ __forceinline__ unsigned short f32_bf16_rne(float f) {
    unsigned u = __float_as_uint(f);
    return (unsigned short)((u + 0x7FFFu + ((u >> 16) & 1u)) >> 16);
}
__device__ __forceinline__ float bf16_f32(unsigned short h) {
    return __uint_as_float(((unsigned)h) << 16);
}

// raw v_exp_f32: bit-identical to exp2f for our argument range [-0.25, 0]
__device__ __forceinline__ float exp2_hw(float x) {
#if __has_builtin(__builtin_amdgcn_exp2f)
    return __builtin_amdgcn_exp2f(x);
#else
    float r;
    asm("v_exp_f32 %0, %1" : "=v"(r) : "v"(x));
    return r;
#endif
}

// single-instruction xor-lane shuffles (masks <= 16): ds_swizzle BitMode
#define SWZ_XOR1(x)  __int_as_float(__builtin_amdgcn_ds_swizzle(__float_as_int(x), 0x041F))
#define SWZ_XOR2(x)  __int_as_float(__builtin_amdgcn_ds_swizzle(__float_as_int(x), 0x081F))
#define SWZ_XOR4(x)  __int_as_float(__builtin_amdgcn_ds_swizzle(__float_as_int(x), 0x101F))
#define SWZ_XOR8(x)  __int_as_float(__builtin_amdgcn_ds_swizzle(__float_as_int(x), 0x201F))
#define SWZ_XOR16(x) __int_as_float(__builtin_amdgcn_ds_swizzle(__float_as_int(x), 0x401F))

// ---- prep v2: 8 threads/row, coalesced 32B loads, 16B ushort8 stores
// (R8, passed; bit-identical split bytes + norms).
__global__ void prep_kernel(const float* __restrict__ x, const float* __restrict__ y,
                            unsigned short* __restrict__ Xh, unsigned short* __restrict__ Xl,
                            unsigned short* __restrict__ Yh, unsigned short* __restrict__ Yl,
                            float* __restrict__ nx, float* __restrict__ ny) {
    int gtid = blockIdx.x * 256 + threadIdx.x;   // 0..131071 = 16384 rows x 8
    int r = gtid >> 3;
    int m = gtid & 7;                            // handles k4 = {2m, 2m+1}
    int isY = r >= NPTS;
    int rr = isY ? r - NPTS : r;
    const float4* Rg = (const float4*)((isY ? y : x) + (size_t)rr * DIM);
    unsigned short* Hh = isY ? Yh : Xh;
    unsigned short* Hl = isY ? Yl : Xl;
    const int t16 = rr >> 4, mrow = rr & 15;
    float4 v0 = Rg[2 * m];
    float4 v1 = Rg[2 * m + 1];
    u16x8 h, l;
    h[0] = f32_bf16_rne(v0.x); l[0] = f32_bf16_rne(v0.x - bf16_f32(h[0]));
    h[1] = f32_bf16_rne(v0.y); l[1] = f32_bf16_rne(v0.y - bf16_f32(h[1]));
    h[2] = f32_bf16_rne(v0.z); l[2] = f32_bf16_rne(v0.z - bf16_f32(h[2]));
    h[3] = f32_bf16_rne(v0.w); l[3] = f32_bf16_rne(v0.w - bf16_f32(h[3]));
    h[4] = f32_bf16_rne(v1.x); l[4] = f32_bf16_rne(v1.x - bf16_f32(h[4]));
    h[5] = f32_bf16_rne(v1.y); l[5] = f32_bf16_rne(v1.y - bf16_f32(h[5]));
    h[6] = f32_bf16_rne(v1.z); l[6] = f32_bf16_rne(v1.z - bf16_f32(h[6]));
    h[7] = f32_bf16_rne(v1.w); l[7] = f32_bf16_rne(v1.w - bf16_f32(h[7]));
    int off = t16 * 1024 + (m >> 2) * 512 + (m & 3) * 128 + mrow * 8;
    *(u16x8*)(Hh + off) = h;
    *(u16x8*)(Hl + off) = l;
    float s0 = v0.x * v0.x;
    s0 = fmaf(v0.y, v0.y, s0); s0 = fmaf(v0.z, v0.z, s0); s0 = fmaf(v0.w, v0.w, s0);
    float s1 = v1.x * v1.x;
    s1 = fmaf(v1.y, v1.y, s1); s1 = fmaf(v1.z, v1.z, s1); s1 = fmaf(v1.w, v1.w, s1);
    float s = s0 + s1;
    s = s + SWZ_XOR1(s);
    s = s + SWZ_XOR2(s);
    s = s + SWZ_XOR4(s);
    if (m == 0) { if (isY) ny[rr] = s; else nx[rr] = s; }
}

// ---- main tile kernel: R3 verbatim (best measured, 72.0us).
// 16x16x32 MFMA, 8 independent acc chains (the ILP that 32x32 lost),
// hoisted A+B fragments, XCD-chunked block swizzle, setprio cluster.
__global__ __launch_bounds__(512, 3) void mmd_tile_kernel(
    const unsigned short* __restrict__ Xh, const unsigned short* __restrict__ Xl,
    const unsigned short* __restrict__ Yh, const unsigned short* __restrict__ Yl,
    const float* __restrict__ nx, const float* __restrict__ ny,
    float* __restrict__ leafs)
{
    // XCD-aware bijective swizzle: 8320 blocks = 8 XCDs x 1040 exactly.
    int id  = blockIdx.x + 65 * (blockIdx.y + 64 * blockIdx.z);  // 0..8319
    int nid = (id & 7) * 1040 + (id >> 3);
    int zb  = nid >= 4160;
    int rem = nid - zb * 4160;          // 0..4159
    int gj  = rem / 65;
    int gi  = rem - gj * 65;

    int zz, bx, by;
    if (zb == 1) {
        if (gi >= 64) return;
        zz = 2; bx = gi; by = gj;
    } else if (gi > gj) {
        zz = 0; by = gj; bx = gi - 1;
    } else {
        zz = 1; by = gi; bx = gj;
    }

    __shared__ float rowpart[2][BT];       // [cblk half][row]
    __shared__ float colpart[4][BT];       // [row quarter][col]

    const int t = threadIdx.x;
    const size_t arow = (size_t)by * BT;
    const size_t brow = (size_t)bx * BT;
    const int cb = bx;

    const unsigned short* pAh = (zz == 1) ? Yh : Xh;
    const unsigned short* pAl = (zz == 1) ? Yl : Xl;
    const unsigned short* pBh = (zz == 0) ? Xh : Yh;
    const unsigned short* pBl = (zz == 0) ? Xl : Yl;
    const float* nA = (zz == 1) ? ny : nx;
    const float* nB = (zz == 0) ? nx : ny;

    const int lane = t & 63;
    const int wv   = t >> 6;               // 0..7
    const int mrow = lane & 15;
    const int quad = lane >> 4;
    const int rblk = (wv & 3) << 5;        // 0,32,64,96
    const int cblk = (wv >> 2) << 6;       // 0,64

    const int aT = by * 8 + (wv & 3) * 2;
    const int bT = bx * 8 + (wv >> 2) * 4;
    const int lsub = quad * 128 + mrow * 8;

    const bool domirror = (zz < 2) && (bx > by);

    // norms straight from global (L2-resident, 16-lane broadcast pattern)
    float sa[8];
    #pragma unroll
    for (int rt = 0; rt < 2; ++rt)
        #pragma unroll
        for (int i = 0; i < 4; ++i)
            sa[rt * 4 + i] = nA[arow + rblk + rt * 16 + quad * 4 + i];
    float sb[4];
    #pragma unroll
    for (int ct = 0; ct < 4; ++ct)
        sb[ct] = nB[brow + cblk + ct * 16 + mrow];

    // A fragments (8 x bf16x8 = 32 VGPR)
    bf16x8 fAh[2][2], fAl[2][2];
    #pragma unroll
    for (int rt = 0; rt < 2; ++rt)
        #pragma unroll
        for (int kc = 0; kc < 2; ++kc) {
            int off = (aT + rt) * 1024 + kc * 512 + lsub;
            fAh[rt][kc] = *(const bf16x8*)(pAh + off);
            fAl[rt][kc] = *(const bf16x8*)(pAl + off);
        }

    // ALL B fragments hoisted (16 x bf16x8 = 64 VGPR)
    bf16x8 fBh0[4], fBh1[4], fBl0[4], fBl1[4];
    #pragma unroll
    for (int ct = 0; ct < 4; ++ct) {
        int boff = (bT + ct) * 1024 + lsub;
        fBh0[ct] = *(const bf16x8*)(pBh + boff);
        fBh1[ct] = *(const bf16x8*)(pBh + boff + 512);
        fBl0[ct] = *(const bf16x8*)(pBl + boff);
        fBl1[ct] = *(const bf16x8*)(pBl + boff + 512);
    }

    const float SCL = (float)(-1.4426950408889634 / 4096.0);
    float rs01[2][4] = {{0.f,0.f,0.f,0.f},{0.f,0.f,0.f,0.f}};
    float rs23[2][4] = {{0.f,0.f,0.f,0.f},{0.f,0.f,0.f,0.f}};
    float cs[4];

    #pragma unroll
    for (int ct = 0; ct < 4; ++ct) {
        bf16x8 bh0 = fBh0[ct];
        bf16x8 bh1 = fBh1[ct];
        bf16x8 bl0 = fBl0[ct];
        bf16x8 bl1 = fBl1[ct];

        f32x4 c0 = (f32x4){0.f, 0.f, 0.f, 0.f};
        f32x4 c1 = (f32x4){0.f, 0.f, 0.f, 0.f};
        __builtin_amdgcn_s_setprio(1);
        c0 = __builtin_amdgcn_mfma_f32_16x16x32_bf16(fAh[0][0], bh0, c0, 0, 0, 0);
        c0 = __builtin_amdgcn_mfma_f32_16x16x32_bf16(fAh[0][0], bl0, c0, 0, 0, 0);
        c0 = __builtin_amdgcn_mfma_f32_16x16x32_bf16(fAl[0][0], bh0, c0, 0, 0, 0);
        c0 = __builtin_amdgcn_mfma_f32_16x16x32_bf16(fAh[0][1], bh1, c0, 0, 0, 0);
        c0 = __builtin_amdgcn_mfma_f32_16x16x32_bf16(fAh[0][1], bl1, c0, 0, 0, 0);
        c0 = __builtin_amdgcn_mfma_f32_16x16x32_bf16(fAl[0][1], bh1, c0, 0, 0, 0);
        c1 = __builtin_amdgcn_mfma_f32_16x16x32_bf16(fAh[1][0], bh0, c1, 0, 0, 0);
        c1 = __builtin_amdgcn_mfma_f32_16x16x32_bf16(fAh[1][0], bl0, c1, 0, 0, 0);
        c1 = __builtin_amdgcn_mfma_f32_16x16x32_bf16(fAl[1][0], bh0, c1, 0, 0, 0);
        c1 = __builtin_amdgcn_mfma_f32_16x16x32_bf16(fAh[1][1], bh1, c1, 0, 0, 0);
        c1 = __builtin_amdgcn_mfma_f32_16x16x32_bf16(fAh[1][1], bl1, c1, 0, 0, 0);
        c1 = __builtin_amdgcn_mfma_f32_16x16x32_bf16(fAl[1][1], bh1, c1, 0, 0, 0);
        __builtin_amdgcn_s_setprio(0);

        float k0[4], k1[4];
        #pragma unroll
        for (int i = 0; i < 4; ++i) {
            float d0  = c0[i];
            float s20 = sa[i] + sb[ct];
            k0[i] = exp2_hw((s20 - 2.0f * d0) * SCL);
            float d1  = c1[i];
            float s21 = sa[4 + i] + sb[ct];
            k1[i] = exp2_hw((s21 - 2.0f * d1) * SCL);
        }
        if (ct < 2) {
            #pragma unroll
            for (int i = 0; i < 4; ++i) { rs01[0][i] += k0[i]; rs01[1][i] += k1[i]; }
        } else {
            #pragma unroll
            for (int i = 0; i < 4; ++i) { rs23[0][i] += k0[i]; rs23[1][i] += k1[i]; }
        }
        if (domirror)
            cs[ct] = ((k0[0] + k0[1]) + (k0[2] + k0[3]))
                   + ((k1[0] + k1[1]) + (k1[2] + k1[3]));
    }

    float rs[2][4];
    #pragma unroll
    for (int rt = 0; rt < 2; ++rt)
        #pragma unroll
        for (int i = 0; i < 4; ++i)
            rs[rt][i] = rs01[rt][i] + rs23[rt][i];

    const int b0 = lane & 1;
    const int b1 = (lane >> 1) & 1;
    const int b2 = (lane >> 2) & 1;
    const int b3 = (lane >> 3) & 1;

    // ---- row reduce: split-butterfly over the 16 mrow lanes
    float a4[4];
    #pragma unroll
    for (int i = 0; i < 4; ++i) {
        float snd = b3 ? rs[0][i] : rs[1][i];
        float rcv = SWZ_XOR8(snd);
        a4[i] = (b3 ? rs[1][i] : rs[0][i]) + rcv;      // keep rt = b3
    }
    float a2[2];
    #pragma unroll
    for (int j = 0; j < 2; ++j) {
        float snd = b2 ? a4[j] : a4[2 + j];
        float rcv = SWZ_XOR4(snd);
        a2[j] = (b2 ? a4[2 + j] : a4[j]) + rcv;        // keep i-high = b2
    }
    {
        float snd = b1 ? a2[0] : a2[1];
        float rcv = SWZ_XOR2(snd);
        float a1  = (b1 ? a2[1] : a2[0]) + rcv;        // i = b2*2 + b1
        float r64 = a1 + SWZ_XOR1(a1);                 // full 64-col half-sum
        if (b0 == 0)
            rowpart[wv >> 2][rblk + b3 * 16 + quad * 4 + b2 * 2 + b1] = r64;
    }

    // ---- col reduce (mirror tiles): split-butterfly over the 4 quads
    if (domirror) {
        const int b4 = (lane >> 4) & 1;
        const int b5 = (lane >> 5) & 1;
        float c2[2];
        #pragma unroll
        for (int j = 0; j < 2; ++j) {
            float snd = b4 ? cs[j] : cs[2 + j];
            float rcv = SWZ_XOR16(snd);
            c2[j] = (b4 ? cs[2 + j] : cs[j]) + rcv;    // keep ct-high = b4
        }
        float snd = b5 ? c2[0] : c2[1];
        float rcv = __shfl_xor(snd, 32);
        float c1v = (b5 ? c2[1] : c2[0]) + rcv;        // ct = b4*2 + b5
        colpart[wv & 3][cblk + (b4 * 2 + b5) * 16 + mrow] = c1v;
    }
    __syncthreads();

    // ---- combine halves/quarters, write leafs
    if (t < BT) {
        leafs[((size_t)zz * 64 + cb) * 8192 + arow + t] = rowpart[0][t] + rowpart[1][t];
        if (domirror) {
            leafs[((size_t)zz * 64 + by) * 8192 + brow + t] =
                (colpart[0][t] + colpart[1][t]) + (colpart[2][t] + colpart[3][t]);
        }
    }
}

// Phase B: rowsum, 4 threads/row, bit-exact split (R5 verbatim)
__global__ void rowsum_kernel(const float* __restrict__ leafs, float* __restrict__ rowsums) {
    const int t = threadIdx.x;             // 0..255
    const int wv = t >> 6;                 // wave 0..3
    const int lane = t & 63;
    const int p = lane >> 4;               // leaf-quarter 0..3
    const int rlo = lane & 15;
    const int gr = blockIdx.x * 64 + wv * 16 + rlo;   // 0..24575
    const int z = gr >> 13;
    const int r = gr & 8191;
    const float* base = leafs + ((size_t)z * 64 + p * 16) * 8192 + r;
    float v[16];
    #pragma unroll
    for (int i = 0; i < 16; ++i) v[i] = base[(size_t)i * 8192];
    #pragma unroll
    for (int n = 8; n >= 1; n >>= 1)
        #pragma unroll
        for (int i = 0; i < 16; ++i)
            if (i < n) v[i] = v[2*i] + v[2*i+1];
    float s = v[0];
    float u = s + SWZ_XOR16(s);            // S0+S1 | S2+S3
    float w = u + __shfl_xor(u, 32);       // (S0+S1)+(S2+S3)
    if (p == 0) rowsums[gr] = w;
}

// Phase C+D fused, 3 parallel z-groups (R7 verbatim, known-good)
__global__ void colsum_kernel(const float* __restrict__ rowsums, float* __restrict__ out) {
    __shared__ float L[3][256];
    __shared__ float m[3];
    const int t  = threadIdx.x;            // 0..767
    const int z  = t >> 8;                 // 0..2
    const int tz = t & 255;
    {
        const float4* src = (const float4*)(rowsums + z * 8192);
        float w[32];
        #pragma unroll
        for (int i = 0; i < 8; ++i) {
            float4 q = src[tz * 8 + i];
            w[4*i+0] = q.x; w[4*i+1] = q.y; w[4*i+2] = q.z; w[4*i+3] = q.w;
        }
        #pragma unroll
        for (int n = 16; n >= 1; n >>= 1)
            #pragma unroll
            for (int i = 0; i < 32; ++i)
                if (i < n) w[i] = w[2*i] + w[2*i+1];
        L[z][tz] = w[0];
    }
    __syncthreads();
    for (int n = 128; n >= 1; n >>= 1) {
        float u = 0.f;
        if (tz < n) u = L[z][2*tz] + L[z][2*tz+1];
        __syncthreads();
        if (tz < n) L[z][tz] = u;
        __syncthreads();
    }
    if (tz == 0) m[z] = L[z][0] * (1.0f / 67108864.0f);
    __syncthreads();
    if (t == 0) {
        float t1 = m[0] + m[1];
        out[0] = t1 - 2.0f * m[2];
    }
}

extern "C" void kernel_launch(void* const* d_in, const int* in_sizes, int n_in,
                              void* d_out, int out_size, void* d_ws, size_t ws_size,
                              hipStream_t stream) {
    const float* x = (const float*)d_in[0];
    const float* y = (const float*)d_in[1];
    float* wsf     = (float*)d_ws;
    float* leafs   = wsf + LEAF_F;
    float* rowsums = wsf + ROWS_F;
    float* nx      = wsf + NX_F;
    float* ny      = wsf + NY_F;
    unsigned short* Xh = (unsigned short*)(wsf + SPLIT_F);
    unsigned short* Xl = Xh + SPLIT_ELEMS;
    unsigned short* Yh = Xl + SPLIT_ELEMS;
    unsigned short* Yl = Yh + SPLIT_ELEMS;

    prep_kernel<<<512, 256, 0, stream>>>(x, y, Xh, Xl, Yh, Yl, nx, ny);
    dim3 grid(65, 64, 2);
    mmd_tile_kernel<<<grid, 512, 0, stream>>>(Xh, Xl, Yh, Yl, nx, ny, leafs);
    rowsum_kernel<<<384, 256, 0, stream>>>(leafs, rowsums);
    colsum_kernel<<<1, 768, 0, stream>>>(rowsums, (float*)d_out);
}